// Round 2
// baseline (162.187 us; speedup 1.0000x reference)
//
#include <hip/hip_runtime.h>

// Problem constants (from reference): B=64, L=512, H=768, W=255
#define B_ 64
#define L_ 512
#define H_ 768
#define W_ 255
#define H4 (H_ / 4)       // 192 float4 per token row
#define WPB 16            // words per block
#define NCHUNK 16         // ceil(W_/WPB); chunk id NCHUNK is the CLS-copy slot

// One fused kernel.
// grid = (NCHUNK+1, B), block = 192 threads (3 waves), thread t owns float4 column t.
// Each block recomputes the word-start prefix sum for its batch via an in-wave
// shuffle scan (redundant across the 3 waves and 16 chunks, but it's ~1 KB of
// L2-hit loads + 24 shuffles — noise), then streams its 16 words' token rows.
__global__ __launch_bounds__(H4) void wordrep_fused(
        const float* __restrict__ seq,
        const int* __restrict__ lengths,
        float* __restrict__ cls_out,
        float* __restrict__ ctx_out) {
    int chunk = blockIdx.x;
    int b     = blockIdx.y;
    int t     = threadIdx.x;          // 0..191
    const float4* base = (const float4*)(seq + (size_t)b * L_ * H_);

    if (chunk == NCHUNK) {
        // cls_output[b,:] = seq[b, 0, :]
        ((float4*)cls_out)[(size_t)b * H4 + t] = base[t];
        return;
    }

    int w0 = chunk * WPB;
    int nw = min(WPB, W_ - w0);       // 16, except last chunk = 15
    int lane = t & 63;
    const int* len = lengths + b * W_;

    // Shuffle-scan prefix sum of lengths[0 .. w0+nw) to get word starts.
    // After the loop, lane (w0+j)&63 holds word w0+j's start/len (set in the
    // final 64-chunk iteration; w0%64 + nw <= 64 always since WPB=16).
    int myStart = 0, myLen = 0;
    int carry = 1;                    // word 0 starts at token 1 (CLS at 0)
    int lim = w0 + nw;                // lim <= W_, so loads stay in bounds
    for (int basew = 0; basew < lim; basew += 64) {
        int i = basew + lane;
        int v = (i < lim) ? len[i] : 0;
        int s = v;
        #pragma unroll
        for (int off = 1; off < 64; off <<= 1) {
            int u = __shfl_up(s, off, 64);
            if (lane >= off) s += u;
        }
        if (i >= w0 && i < lim) { myStart = carry + (s - v); myLen = v; }
        carry += __shfl(s, 63, 64);
    }

    int srcBase = w0 & 63;            // lane of word w0
    float4* out = (float4*)ctx_out + ((size_t)b * W_ + w0) * H4 + t;

    #pragma unroll 4
    for (int j = 0; j < nw; ++j) {
        int sj = __shfl(myStart, srcBase + j, 64);  // wave-uniform
        int lj = __shfl(myLen,  srcBase + j, 64);
        float4 acc = make_float4(0.f, 0.f, 0.f, 0.f);
        if (lj > 0) {
            int end = sj + lj;
            if (end > L_) end = L_;   // safety clamp (can't trigger for this data)
            for (int tok = sj; tok < end; ++tok) {
                float4 v = base[(size_t)tok * H4 + t];
                acc.x += v.x; acc.y += v.y; acc.z += v.z; acc.w += v.w;
            }
            float inv = 1.0f / (float)lj;
            acc.x *= inv; acc.y *= inv; acc.z *= inv; acc.w *= inv;
        }
        out[(size_t)j * H4] = acc;    // zeros when lj <= 0, matching reference
    }
}

extern "C" void kernel_launch(void* const* d_in, const int* in_sizes, int n_in,
                              void* d_out, int out_size, void* d_ws, size_t ws_size,
                              hipStream_t stream) {
    const float* seq     = (const float*)d_in[0];   // (B, L, H) fp32
    const int*   lengths = (const int*)d_in[1];     // (B, W) int32

    float* cls_out = (float*)d_out;                        // (B, H)
    float* ctx_out = (float*)d_out + (size_t)B_ * H_;      // (B, W, H)

    dim3 grid(NCHUNK + 1, B_);   // 17 x 64 = 1088 blocks
    wordrep_fused<<<grid, H4, 0, stream>>>(seq, lengths, cls_out, ctx_out);
}

// Round 3
// 159.147 us; speedup vs baseline: 1.0191x; 1.0191x over previous
//
#include <hip/hip_runtime.h>

// Problem constants (from reference): B=64, L=512, H=768, W=255
#define B_ 64
#define L_ 512
#define H_ 768
#define W_ 255
#define H4 (H_ / 4)       // 192 float4 per token row
#define WPB 8             // words per block
#define NCHUNK 32         // ceil(W_/WPB); chunk id NCHUNK is the CLS-copy slot

// One fused kernel, batched-load version.
// grid = (NCHUNK+1, B), block = 192 threads (3 waves), thread t owns float4 col t.
// Key idea: words_lengths in this problem are {1,2}; for each of the 8 words we
// unconditionally issue TWO row loads (second = start+1 if len>1, else a dup
// that hits L1). Fully unrolled -> 16 independent global_load_dwordx4 in
// flight per wave (no per-token waitcnt serialization). A guarded fallback
// loop handles len>2 for generality (never taken with this data).
__global__ __launch_bounds__(H4) void wordrep_fused(
        const float* __restrict__ seq,
        const int* __restrict__ lengths,
        float* __restrict__ cls_out,
        float* __restrict__ ctx_out) {
    int chunk = blockIdx.x;
    int b     = blockIdx.y;
    int t     = threadIdx.x;          // 0..191
    const float4* base = (const float4*)(seq + (size_t)b * L_ * H_);

    if (chunk == NCHUNK) {
        // cls_output[b,:] = seq[b, 0, :]
        ((float4*)cls_out)[(size_t)b * H4 + t] = base[t];
        return;
    }

    int w0 = chunk * WPB;
    int nw = min(WPB, W_ - w0);       // 8, except last chunk = 7
    int lane = t & 63;
    const int* len = lengths + b * W_;

    // Shuffle-scan prefix sum of lengths[0 .. w0+nw) to get word starts.
    // Lane (w0+j)&63 ends holding word w0+j's start/len (w0%64 + nw <= 64).
    int myStart = 0, myLen = 0;
    int carry = 1;                    // word 0 starts at token 1 (CLS at 0)
    int lim = w0 + nw;
    for (int basew = 0; basew < lim; basew += 64) {
        int i = basew + lane;
        int v = (i < lim) ? len[i] : 0;
        int s = v;
        #pragma unroll
        for (int off = 1; off < 64; off <<= 1) {
            int u = __shfl_up(s, off, 64);
            if (lane >= off) s += u;
        }
        if (i >= w0 && i < lim) { myStart = carry + (s - v); myLen = v; }
        carry += __shfl(s, 63, 64);
    }

    int srcBase = w0 & 63;            // lane of word w0

    // Broadcast all 8 (start, len) pairs to the whole wave.
    int s_[WPB], l_[WPB];
    #pragma unroll
    for (int j = 0; j < WPB; ++j) {
        s_[j] = __shfl(myStart, srcBase + j, 64);
        l_[j] = __shfl(myLen,   srcBase + j, 64);
    }

    // Issue all 16 row loads back-to-back (no intervening waitcnt).
    float4 a0[WPB], a1[WPB];
    #pragma unroll
    for (int j = 0; j < WPB; ++j) {
        int t0 = min(max(s_[j], 0), L_ - 1);                      // clamped-safe
        int t1 = min(max(s_[j] + (l_[j] > 1 ? 1 : 0), 0), L_ - 1);
        a0[j] = base[(size_t)t0 * H4 + t];
        a1[j] = base[(size_t)t1 * H4 + t];
    }

    float4* out = (float4*)ctx_out + ((size_t)b * W_ + w0) * H4 + t;

    #pragma unroll
    for (int j = 0; j < WPB; ++j) {
        int lj = l_[j];
        float m1 = (lj > 1) ? 1.0f : 0.0f;
        float4 acc;
        acc.x = a0[j].x + m1 * a1[j].x;
        acc.y = a0[j].y + m1 * a1[j].y;
        acc.z = a0[j].z + m1 * a1[j].z;
        acc.w = a0[j].w + m1 * a1[j].w;
        if (lj > 2) {                 // generality fallback; never taken here
            int end = min(s_[j] + lj, L_);
            for (int tok = s_[j] + 2; tok < end; ++tok) {
                float4 v = base[(size_t)tok * H4 + t];
                acc.x += v.x; acc.y += v.y; acc.z += v.z; acc.w += v.w;
            }
        }
        float inv = (lj > 0) ? (1.0f / (float)lj) : 0.0f;
        acc.x *= inv; acc.y *= inv; acc.z *= inv; acc.w *= inv;
        if (lj <= 0) { acc.x = 0.f; acc.y = 0.f; acc.z = 0.f; acc.w = 0.f; }
        if (j < nw) out[(size_t)j * H4] = acc;
    }
}

extern "C" void kernel_launch(void* const* d_in, const int* in_sizes, int n_in,
                              void* d_out, int out_size, void* d_ws, size_t ws_size,
                              hipStream_t stream) {
    const float* seq     = (const float*)d_in[0];   // (B, L, H) fp32
    const int*   lengths = (const int*)d_in[1];     // (B, W) int32

    float* cls_out = (float*)d_out;                        // (B, H)
    float* ctx_out = (float*)d_out + (size_t)B_ * H_;      // (B, W, H)

    dim3 grid(NCHUNK + 1, B_);   // 33 x 64 = 2112 blocks
    wordrep_fused<<<grid, H4, 0, stream>>>(seq, lengths, cls_out, ctx_out);
}